// Round 1
// baseline (227.308 us; speedup 1.0000x reference)
//
#include <hip/hip_runtime.h>

#define NN 500000
#define KK 3
#define EE (NN * KK)
#define FD 2
#define HH 64
#define NC 8
#define NIN 16
#define EIN 8

__device__ __forceinline__ float leaky(float x) { return x >= 0.0f ? x : 0.1f * x; }

// Fused input projections: h0 = node_feat@Wn+bn, e = edge_attr@We+be
__global__ __launch_bounds__(256) void prep_kernel(
    const float* __restrict__ node_feat, const float* __restrict__ edge_attr,
    const float* __restrict__ Wn, const float* __restrict__ bn,
    const float* __restrict__ We, const float* __restrict__ be,
    float* __restrict__ h, float* __restrict__ e)
{
    int idx = blockIdx.x * blockDim.x + threadIdx.x;
    if (idx < NN) {
        const float4* x4 = (const float4*)(node_feat + (size_t)idx * NIN);
        float4 v0 = x4[0], v1 = x4[1], v2 = x4[2], v3 = x4[3];
        float xs[16] = {v0.x, v0.y, v0.z, v0.w, v1.x, v1.y, v1.z, v1.w,
                        v2.x, v2.y, v2.z, v2.w, v3.x, v3.y, v3.z, v3.w};
        float a0 = bn[0], a1 = bn[1];
#pragma unroll
        for (int i = 0; i < NIN; i++) {
            a0 = fmaf(xs[i], Wn[i * FD + 0], a0);
            a1 = fmaf(xs[i], Wn[i * FD + 1], a1);
        }
        ((float2*)h)[idx] = make_float2(a0, a1);
    } else if (idx < NN + EE) {
        int eidx = idx - NN;
        const float4* x4 = (const float4*)(edge_attr + (size_t)eidx * EIN);
        float4 v0 = x4[0], v1 = x4[1];
        float xs[8] = {v0.x, v0.y, v0.z, v0.w, v1.x, v1.y, v1.z, v1.w};
        float a0 = be[0], a1 = be[1];
#pragma unroll
        for (int i = 0; i < EIN; i++) {
            a0 = fmaf(xs[i], We[i * FD + 0], a0);
            a1 = fmaf(xs[i], We[i * FD + 1], a1);
        }
        ((float2*)e)[eidx] = make_float2(a0, a1);
    }
}

// One GNN layer: per-node thread does 3 message MLPs (4->64->2, hidden summed
// across edges before W2), segment-sum (implicit: edges 3i..3i+2 belong to
// node i), update MLP, residual+ReLU. If `out` != null, also runs the fused
// final MLP (2->64->8) and writes logits instead of h_out.
__global__ __launch_bounds__(256) void layer_kernel(
    const float* __restrict__ h_in, const float* __restrict__ e,
    const int* __restrict__ nbr,
    const float* __restrict__ mW1g, const float* __restrict__ mb1g,
    const float* __restrict__ mW2g, const float* __restrict__ mb2g,
    const float* __restrict__ uW1g, const float* __restrict__ ub1g,
    const float* __restrict__ uW2g, const float* __restrict__ ub2g,
    float* __restrict__ h_out,
    const float* __restrict__ fW1g, const float* __restrict__ fb1g,
    const float* __restrict__ fW2g, const float* __restrict__ fb2g,
    float* __restrict__ out)
{
    __shared__ float sW1[4 * HH], sb1[HH], sW2[2 * HH], sb2[2];
    __shared__ float uW1[4 * HH], ub1[HH], uW2[2 * HH], ub2[2];
    __shared__ float fW1[2 * HH], fb1[HH], fW2[HH * NC], fb2[NC];
    int t = threadIdx.x;
    // blockDim.x == 256 == 4*HH
    sW1[t] = mW1g[t];
    uW1[t] = uW1g[t];
    if (t < HH) { sb1[t] = mb1g[t]; ub1[t] = ub1g[t]; }
    if (t < 2 * HH) { sW2[t] = mW2g[t]; uW2[t] = uW2g[t]; }
    if (t < 2) { sb2[t] = mb2g[t]; ub2[t] = ub2g[t]; }
    if (out) {
        if (t < 2 * HH) fW1[t] = fW1g[t];
        if (t < HH) fb1[t] = fb1g[t];
        if (t < NC) fb2[t] = fb2g[t];
        fW2[t] = fW2g[t];
        fW2[t + 256] = fW2g[t + 256];
    }
    __syncthreads();

    int i = blockIdx.x * blockDim.x + t;
    if (i >= NN) return;

    float2 hh = ((const float2*)h_in)[i];
    int base = i * KK;
    int n0 = nbr[base + 0], n1 = nbr[base + 1], n2 = nbr[base + 2];
    float2 hn0 = ((const float2*)h_in)[n0];
    float2 hn1 = ((const float2*)h_in)[n1];
    float2 hn2 = ((const float2*)h_in)[n2];
    float2 e0 = ((const float2*)e)[base + 0];
    float2 e1 = ((const float2*)e)[base + 1];
    float2 e2 = ((const float2*)e)[base + 2];

    // aggr = (sum_e leaky(x_e W1 + b1)) @ W2 + 3*b2   (linearity of segment_sum)
    float a0 = 3.0f * sb2[0], a1 = 3.0f * sb2[1];
#pragma unroll 8
    for (int j = 0; j < HH; j++) {
        float w0 = sW1[j], w1 = sW1[HH + j], w2 = sW1[2 * HH + j], w3 = sW1[3 * HH + j];
        float bb = sb1[j];
        float t0 = fmaf(e0.x, w0, fmaf(e0.y, w1, fmaf(hn0.x, w2, fmaf(hn0.y, w3, bb))));
        float t1 = fmaf(e1.x, w0, fmaf(e1.y, w1, fmaf(hn1.x, w2, fmaf(hn1.y, w3, bb))));
        float t2 = fmaf(e2.x, w0, fmaf(e2.y, w1, fmaf(hn2.x, w2, fmaf(hn2.y, w3, bb))));
        float ts = leaky(t0) + leaky(t1) + leaky(t2);
        a0 = fmaf(ts, sW2[2 * j + 0], a0);
        a1 = fmaf(ts, sW2[2 * j + 1], a1);
    }

    // update MLP on concat(h, aggr)
    float u0 = ub2[0], u1 = ub2[1];
#pragma unroll 8
    for (int j = 0; j < HH; j++) {
        float tt = fmaf(hh.x, uW1[j],
                   fmaf(hh.y, uW1[HH + j],
                   fmaf(a0, uW1[2 * HH + j],
                   fmaf(a1, uW1[3 * HH + j], ub1[j]))));
        tt = leaky(tt);
        u0 = fmaf(tt, uW2[2 * j + 0], u0);
        u1 = fmaf(tt, uW2[2 * j + 1], u1);
    }
    float nh0 = fmaxf(hh.x + u0, 0.0f);
    float nh1 = fmaxf(hh.y + u1, 0.0f);

    if (!out) {
        ((float2*)h_out)[i] = make_float2(nh0, nh1);
    } else {
        float o[NC];
#pragma unroll
        for (int c = 0; c < NC; c++) o[c] = fb2[c];
#pragma unroll 4
        for (int j = 0; j < HH; j++) {
            float tt = leaky(fmaf(nh0, fW1[j], fmaf(nh1, fW1[HH + j], fb1[j])));
#pragma unroll
            for (int c = 0; c < NC; c++) o[c] = fmaf(tt, fW2[j * NC + c], o[c]);
        }
        float4* op = (float4*)(out + (size_t)i * NC);
        op[0] = make_float4(o[0], o[1], o[2], o[3]);
        op[1] = make_float4(o[4], o[5], o[6], o[7]);
    }
}

extern "C" void kernel_launch(void* const* d_in, const int* in_sizes, int n_in,
                              void* d_out, int out_size, void* d_ws, size_t ws_size,
                              hipStream_t stream) {
    const float* node_feat = (const float*)d_in[0];
    const float* edge_attr = (const float*)d_in[1];
    const int* edge_index = (const int*)d_in[2];
    // d_in[3] = batch (unused: single graph, eval mode)
    const float* Wn = (const float*)d_in[4];
    const float* bn = (const float*)d_in[5];
    const float* We = (const float*)d_in[6];
    const float* be = (const float*)d_in[7];
    const float* msgW1 = (const float*)d_in[8];
    const float* msgb1 = (const float*)d_in[9];
    const float* msgW2 = (const float*)d_in[10];
    const float* msgb2 = (const float*)d_in[11];
    const float* updW1 = (const float*)d_in[12];
    const float* updb1 = (const float*)d_in[13];
    const float* updW2 = (const float*)d_in[14];
    const float* updb2 = (const float*)d_in[15];
    const float* finW1 = (const float*)d_in[16];
    const float* finb1 = (const float*)d_in[17];
    const float* finW2 = (const float*)d_in[18];
    const float* finb2 = (const float*)d_in[19];
    float* out = (float*)d_out;

    const int* nbr = edge_index + EE;  // edge_index[1] row

    char* ws = (char*)d_ws;
    float* hA = (float*)ws;                            // NN*2 floats (4 MB)
    float* hB = (float*)(ws + (size_t)NN * 2 * 4);     // NN*2 floats (4 MB)
    float* eP = (float*)(ws + (size_t)NN * 4 * 4);     // EE*2 floats (12 MB)

    const int threads = 256;
    int prep_grid = (NN + EE + threads - 1) / threads;
    prep_kernel<<<prep_grid, threads, 0, stream>>>(node_feat, edge_attr, Wn, bn, We, be, hA, eP);

    int grid = (NN + threads - 1) / threads;
    // layer 0: hA -> hB
    layer_kernel<<<grid, threads, 0, stream>>>(
        hA, eP, nbr,
        msgW1, msgb1, msgW2, msgb2,
        updW1, updb1, updW2, updb2,
        hB, nullptr, nullptr, nullptr, nullptr, nullptr);
    // layer 1 (+ fused final MLP): hB -> out
    layer_kernel<<<grid, threads, 0, stream>>>(
        hB, eP, nbr,
        msgW1 + 4 * HH, msgb1 + HH, msgW2 + 2 * HH, msgb2 + FD,
        updW1 + 4 * HH, updb1 + HH, updW2 + 2 * HH, updb2 + FD,
        nullptr, finW1, finb1, finW2, finb2, out);
}

// Round 3
// 213.935 us; speedup vs baseline: 1.0625x; 1.0625x over previous
//
#include <hip/hip_runtime.h>

#define NN 500000
#define KK 3
#define EE (NN * KK)
#define HH 64
#define NC 8
#define NIN 16
#define EIN 8

typedef __attribute__((ext_vector_type(2)))  float sf2;
typedef __attribute__((ext_vector_type(4)))  float sf4;
typedef __attribute__((ext_vector_type(8)))  float sf8;
typedef __attribute__((ext_vector_type(16))) float sf16;

// Guaranteed-scalar loads of wave-uniform weight data (K$-cached, scalar pipe).
__device__ __forceinline__ sf2 sload2(const float* p) {
    sf2 r; asm("s_load_dwordx2 %0, %1, 0x0" : "=s"(r) : "s"(p)); return r;
}
__device__ __forceinline__ sf4 sload4(const float* p) {
    sf4 r; asm("s_load_dwordx4 %0, %1, 0x0" : "=s"(r) : "s"(p)); return r;
}
__device__ __forceinline__ sf8 sload8(const float* p) {
    sf8 r; asm("s_load_dwordx8 %0, %1, 0x0" : "=s"(r) : "s"(p)); return r;
}
__device__ __forceinline__ sf16 sload16(const float* p) {
    sf16 r; asm("s_load_dwordx16 %0, %1, 0x0" : "=s"(r) : "s"(p)); return r;
}

// Wait barriers whose outputs carry the loaded values -> uses can't be
// scheduled above the s_waitcnt.
#define SWAIT1(a)           asm volatile("s_waitcnt lgkmcnt(0)" : "+s"(a))
#define SWAIT2(a,b)         asm volatile("s_waitcnt lgkmcnt(0)" : "+s"(a),"+s"(b))
#define SWAIT5(a,b,c,d,e)   asm volatile("s_waitcnt lgkmcnt(0)" : "+s"(a),"+s"(b),"+s"(c),"+s"(d),"+s"(e))
#define SWAIT6(a,b,c,d,e,f) asm volatile("s_waitcnt lgkmcnt(0)" : "+s"(a),"+s"(b),"+s"(c),"+s"(d),"+s"(e),"+s"(f))

__device__ __forceinline__ float leaky(float x) { return fmaxf(x, 0.1f * x); }

// Fused input projections: h0 = node_feat@Wn+bn, e = edge_attr@We+be
__global__ __launch_bounds__(256) void prep_kernel(
    const float* __restrict__ node_feat, const float* __restrict__ edge_attr,
    const float* __restrict__ Wn, const float* __restrict__ bn,
    const float* __restrict__ We, const float* __restrict__ be,
    float* __restrict__ h, float* __restrict__ ep)
{
    sf16 wn0 = sload16(Wn);        // Wn[i][c]=Wn[2i+c], i=0..7
    sf16 wn1 = sload16(Wn + 16);   // i=8..15
    sf2  bnv = sload2(bn);
    sf16 wev = sload16(We);        // We[i][c]=We[2i+c], i=0..7
    sf2  bev = sload2(be);
    SWAIT5(wn0, wn1, bnv, wev, bev);

    int idx = blockIdx.x * 256 + threadIdx.x;
    if (idx < NN) {
        const float4* x4 = (const float4*)(node_feat + (size_t)idx * NIN);
        float4 v0 = x4[0], v1 = x4[1], v2 = x4[2], v3 = x4[3];
        float xs[16] = {v0.x, v0.y, v0.z, v0.w, v1.x, v1.y, v1.z, v1.w,
                        v2.x, v2.y, v2.z, v2.w, v3.x, v3.y, v3.z, v3.w};
        float a0 = bnv.x, a1 = bnv.y;
#pragma unroll
        for (int i = 0; i < 8; i++) {
            a0 = fmaf(xs[i], wn0[2 * i], a0);
            a1 = fmaf(xs[i], wn0[2 * i + 1], a1);
        }
#pragma unroll
        for (int i = 0; i < 8; i++) {
            a0 = fmaf(xs[8 + i], wn1[2 * i], a0);
            a1 = fmaf(xs[8 + i], wn1[2 * i + 1], a1);
        }
        ((float2*)h)[idx] = make_float2(a0, a1);
    } else if (idx < NN + EE) {
        int eidx = idx - NN;
        const float4* x4 = (const float4*)(edge_attr + (size_t)eidx * EIN);
        float4 v0 = x4[0], v1 = x4[1];
        float xs[8] = {v0.x, v0.y, v0.z, v0.w, v1.x, v1.y, v1.z, v1.w};
        float a0 = bev.x, a1 = bev.y;
#pragma unroll
        for (int i = 0; i < 8; i++) {
            a0 = fmaf(xs[i], wev[2 * i], a0);
            a1 = fmaf(xs[i], wev[2 * i + 1], a1);
        }
        ((float2*)ep)[eidx] = make_float2(a0, a1);
    }
}

// One GNN layer, one thread per node. Weights streamed through SGPRs
// (scalar pipe) in chunks of 8 hidden units; inner loop is pure VALU with
// <=1 SGPR operand per v_fma. No LDS at all.
template<bool FINAL>
__global__ __launch_bounds__(256) void layer_kernel(
    const float* __restrict__ h_in, const float* __restrict__ e,
    const int* __restrict__ nbr,
    const float* __restrict__ mW1, const float* __restrict__ mb1,
    const float* __restrict__ mW2, const float* __restrict__ mb2,
    const float* __restrict__ uW1, const float* __restrict__ ub1,
    const float* __restrict__ uW2, const float* __restrict__ ub2,
    float* __restrict__ h_out,
    const float* __restrict__ fW1, const float* __restrict__ fb1,
    const float* __restrict__ fW2, const float* __restrict__ fb2,
    float* __restrict__ out)
{
    int i = blockIdx.x * 256 + threadIdx.x;
    if (i >= NN) return;

    sf2 mb2v = sload2(mb2);
    sf2 ub2v = sload2(ub2);
    SWAIT2(mb2v, ub2v);

    float2 hh = ((const float2*)h_in)[i];
    int base = i * KK;
    int n0 = nbr[base + 0], n1 = nbr[base + 1], n2 = nbr[base + 2];
    float2 hn0 = ((const float2*)h_in)[n0];
    float2 hn1 = ((const float2*)h_in)[n1];
    float2 hn2 = ((const float2*)h_in)[n2];
    float2 e0 = ((const float2*)e)[base + 0];
    float2 e1 = ((const float2*)e)[base + 1];
    float2 e2 = ((const float2*)e)[base + 2];

    // aggr = (sum_e leaky([e,hn]@W1 + b1)) @ W2 + 3*b2   (linearity of segment_sum)
    float a0 = 3.0f * mb2v.x, a1 = 3.0f * mb2v.y;
#pragma unroll 1
    for (int j0 = 0; j0 < HH; j0 += 8) {
        sf8 w0 = sload8(mW1 + j0);            // W1 row 0 (e.x)
        sf8 w1 = sload8(mW1 + HH + j0);       // row 1 (e.y)
        sf8 w2 = sload8(mW1 + 2 * HH + j0);   // row 2 (hn.x)
        sf8 w3 = sload8(mW1 + 3 * HH + j0);   // row 3 (hn.y)
        sf8 bb = sload8(mb1 + j0);
        sf16 wc = sload16(mW2 + 2 * j0);      // W2[j][0..1], 8 rows
        SWAIT6(w0, w1, w2, w3, bb, wc);
#pragma unroll
        for (int q = 0; q < 8; q++) {
            float t0 = fmaf(e0.x, w0[q], fmaf(e0.y, w1[q], fmaf(hn0.x, w2[q], fmaf(hn0.y, w3[q], bb[q]))));
            float t1 = fmaf(e1.x, w0[q], fmaf(e1.y, w1[q], fmaf(hn1.x, w2[q], fmaf(hn1.y, w3[q], bb[q]))));
            float t2 = fmaf(e2.x, w0[q], fmaf(e2.y, w1[q], fmaf(hn2.x, w2[q], fmaf(hn2.y, w3[q], bb[q]))));
            float ts = leaky(t0) + leaky(t1) + leaky(t2);
            a0 = fmaf(ts, wc[2 * q], a0);
            a1 = fmaf(ts, wc[2 * q + 1], a1);
        }
    }

    // update MLP on concat(h, aggr)
    float u0 = ub2v.x, u1 = ub2v.y;
#pragma unroll 1
    for (int j0 = 0; j0 < HH; j0 += 8) {
        sf8 w0 = sload8(uW1 + j0);
        sf8 w1 = sload8(uW1 + HH + j0);
        sf8 w2 = sload8(uW1 + 2 * HH + j0);
        sf8 w3 = sload8(uW1 + 3 * HH + j0);
        sf8 bb = sload8(ub1 + j0);
        sf16 wc = sload16(uW2 + 2 * j0);
        SWAIT6(w0, w1, w2, w3, bb, wc);
#pragma unroll
        for (int q = 0; q < 8; q++) {
            float tt = fmaf(hh.x, w0[q], fmaf(hh.y, w1[q], fmaf(a0, w2[q], fmaf(a1, w3[q], bb[q]))));
            tt = leaky(tt);
            u0 = fmaf(tt, wc[2 * q], u0);
            u1 = fmaf(tt, wc[2 * q + 1], u1);
        }
    }
    float nh0 = fmaxf(hh.x + u0, 0.0f);
    float nh1 = fmaxf(hh.y + u1, 0.0f);

    if (!FINAL) {
        ((float2*)h_out)[i] = make_float2(nh0, nh1);
    } else {
        sf8 fb2v = sload8(fb2);
        SWAIT1(fb2v);
        float o[NC];
#pragma unroll
        for (int c = 0; c < NC; c++) o[c] = fb2v[c];
#pragma unroll 1
        for (int j0 = 0; j0 < HH; j0 += 4) {
            sf4 p0 = sload4(fW1 + j0);            // fW1[0][j]
            sf4 p1 = sload4(fW1 + HH + j0);       // fW1[1][j]
            sf4 pb = sload4(fb1 + j0);
            sf16 q0 = sload16(fW2 + 8 * j0);      // fW2 rows j0, j0+1
            sf16 q1 = sload16(fW2 + 8 * j0 + 16); // rows j0+2, j0+3
            SWAIT5(p0, p1, pb, q0, q1);
#pragma unroll
            for (int qq = 0; qq < 4; qq++) {
                float tt = leaky(fmaf(nh0, p0[qq], fmaf(nh1, p1[qq], pb[qq])));
#pragma unroll
                for (int c = 0; c < NC; c++) {
                    float wv = (qq < 2) ? q0[8 * qq + c] : q1[8 * (qq - 2) + c];
                    o[c] = fmaf(tt, wv, o[c]);
                }
            }
        }
        float4* op = (float4*)(out + (size_t)i * NC);
        op[0] = make_float4(o[0], o[1], o[2], o[3]);
        op[1] = make_float4(o[4], o[5], o[6], o[7]);
    }
}

extern "C" void kernel_launch(void* const* d_in, const int* in_sizes, int n_in,
                              void* d_out, int out_size, void* d_ws, size_t ws_size,
                              hipStream_t stream) {
    const float* node_feat = (const float*)d_in[0];
    const float* edge_attr = (const float*)d_in[1];
    const int* edge_index = (const int*)d_in[2];
    // d_in[3] = batch (unused: single graph, eval mode)
    const float* Wn = (const float*)d_in[4];
    const float* bn = (const float*)d_in[5];
    const float* We = (const float*)d_in[6];
    const float* be = (const float*)d_in[7];
    const float* msgW1 = (const float*)d_in[8];
    const float* msgb1 = (const float*)d_in[9];
    const float* msgW2 = (const float*)d_in[10];
    const float* msgb2 = (const float*)d_in[11];
    const float* updW1 = (const float*)d_in[12];
    const float* updb1 = (const float*)d_in[13];
    const float* updW2 = (const float*)d_in[14];
    const float* updb2 = (const float*)d_in[15];
    const float* finW1 = (const float*)d_in[16];
    const float* finb1 = (const float*)d_in[17];
    const float* finW2 = (const float*)d_in[18];
    const float* finb2 = (const float*)d_in[19];
    float* out = (float*)d_out;

    const int* nbr = edge_index + EE;  // edge_index[1] row

    char* ws = (char*)d_ws;
    float* hA = (float*)ws;                          // NN*2 floats
    float* hB = (float*)(ws + (size_t)NN * 2 * 4);   // NN*2 floats
    float* eP = (float*)(ws + (size_t)NN * 4 * 4);   // EE*2 floats

    const int threads = 256;
    int prep_grid = (NN + EE + threads - 1) / threads;
    prep_kernel<<<prep_grid, threads, 0, stream>>>(node_feat, edge_attr, Wn, bn, We, be, hA, eP);

    int grid = (NN + threads - 1) / threads;
    // layer 0: hA -> hB
    layer_kernel<false><<<grid, threads, 0, stream>>>(
        hA, eP, nbr,
        msgW1, msgb1, msgW2, msgb2,
        updW1, updb1, updW2, updb2,
        hB, finW1, finb1, finW2, finb2, nullptr);
    // layer 1 (+ fused final MLP): hB -> out
    // Stacked weights are (L, ...): layer 1 offsets = +4*HH (W1: 4x64),
    // +HH (b1), +2*HH (W2: 64x2), +2 (b2).
    layer_kernel<true><<<grid, threads, 0, stream>>>(
        hB, eP, nbr,
        msgW1 + 4 * HH, msgb1 + HH, msgW2 + 2 * HH, msgb2 + 2,
        updW1 + 4 * HH, updb1 + HH, updW2 + 2 * HH, updb2 + 2,
        nullptr, finW1, finb1, finW2, finb2, out);
}

// Round 5
// 204.675 us; speedup vs baseline: 1.1106x; 1.0452x over previous
//
#include <hip/hip_runtime.h>

#define NN 500000
#define KK 3
#define EE (NN * KK)
#define HH 64
#define NC 8
#define NIN 16
#define EIN 8

typedef __attribute__((ext_vector_type(2))) _Float16 h2;
typedef __attribute__((ext_vector_type(2)))  float sf2;
typedef __attribute__((ext_vector_type(8)))  float sf8;
typedef __attribute__((ext_vector_type(16))) float sf16;

// The builtins' own half-pair type (clang spells it __fp16 ext_vector(2)).
using pk_t = decltype(__builtin_amdgcn_cvt_pkrtz(0.f, 0.f));

// Guaranteed-scalar loads of wave-uniform weight data (K$-cached, scalar pipe).
__device__ __forceinline__ sf2 sload2(const float* p) {
    sf2 r; asm("s_load_dwordx2 %0, %1, 0x0" : "=s"(r) : "s"(p)); return r;
}
__device__ __forceinline__ sf8 sload8(const float* p) {
    sf8 r; asm("s_load_dwordx8 %0, %1, 0x0" : "=s"(r) : "s"(p)); return r;
}
__device__ __forceinline__ sf16 sload16(const float* p) {
    sf16 r; asm("s_load_dwordx16 %0, %1, 0x0" : "=s"(r) : "s"(p)); return r;
}
#define SWAIT1(a)       asm volatile("s_waitcnt lgkmcnt(0)" : "+s"(a))
#define SWAIT2(a,b)     asm volatile("s_waitcnt lgkmcnt(0)" : "+s"(a),"+s"(b))
#define SWAIT3(a,b,c)   asm volatile("s_waitcnt lgkmcnt(0)" : "+s"(a),"+s"(b),"+s"(c))
#define SWAIT5(a,b,c,d,e) asm volatile("s_waitcnt lgkmcnt(0)" : "+s"(a),"+s"(b),"+s"(c),"+s"(d),"+s"(e))

#if __has_builtin(__builtin_elementwise_fma)
#define PKFMA(a,b,c) __builtin_elementwise_fma((a),(b),(c))
#else
#define PKFMA(a,b,c) ((a)*(b)+(c))
#endif

__device__ __forceinline__ h2 bch2(float f)        { return __builtin_bit_cast(h2, f); }
__device__ __forceinline__ h2 bch2u(unsigned int u){ return __builtin_bit_cast(h2, u); }
__device__ __forceinline__ h2 dup16(float f) {
    return __builtin_bit_cast(h2, __builtin_amdgcn_cvt_pkrtz(f, f));
}
__device__ __forceinline__ float fdot2(h2 a, h2 b, float c) {
#if __has_builtin(__builtin_amdgcn_fdot2)
    return __builtin_amdgcn_fdot2(__builtin_bit_cast(pk_t, a),
                                  __builtin_bit_cast(pk_t, b), c, false);
#else
    return c + (float)a.x * (float)b.x + (float)a.y * (float)b.y;
#endif
}
__device__ __forceinline__ h2 lk2(h2 x) {
    h2 c = {(_Float16)0.1f, (_Float16)0.1f};
    return __builtin_elementwise_max(x, x * c);
}

// ---- weight packing (one wave, runs once per launch, ~6 KB output) ----
// msg/upd block (per layer,mlp): 8 chunks x 32 dwords:
//   [0:3]=W1row0 pairs, [4:7]=row1, [8:11]=row2, [12:15]=row3,
//   [16:19]=b1 pairs, [20:23]=W2[:,0] pairs, [24:27]=W2[:,1] pairs, [28:31]=pad
// final block: 8 chunks x 48 dwords:
//   [0:3]=fW1row0 pairs, [4:7]=row1, [8:11]=fb1 pairs, [12:15]=pad,
//   [16+jp*8+c] = pack(fW2[j0+2jp][c], fW2[j0+2jp+1][c])
__device__ __forceinline__ float pack2(float a, float b) {
    h2 v; v.x = (_Float16)a; v.y = (_Float16)b;   // RTN conversion for weights
    return __builtin_bit_cast(float, v);
}

__global__ void pack_kernel(
    const float* __restrict__ msgW1, const float* __restrict__ msgb1, const float* __restrict__ msgW2,
    const float* __restrict__ updW1, const float* __restrict__ updb1, const float* __restrict__ updW2,
    const float* __restrict__ finW1, const float* __restrict__ finb1, const float* __restrict__ finW2,
    float* __restrict__ wpack)
{
    int t = threadIdx.x;
    if (t < 32) {
        int l = t >> 4, which = (t >> 3) & 1, c = t & 7;
        const float* W1 = (which ? updW1 : msgW1) + l * 4 * HH;
        const float* b1 = (which ? updb1 : msgb1) + l * HH;
        const float* W2 = (which ? updW2 : msgW2) + l * 2 * HH;
        float* dst = wpack + (l * 2 + which) * 256 + c * 32;
        int j0 = c * 8;
        for (int r = 0; r < 4; r++)
            for (int p = 0; p < 4; p++)
                dst[r * 4 + p] = pack2(W1[r * HH + j0 + 2 * p], W1[r * HH + j0 + 2 * p + 1]);
        for (int p = 0; p < 4; p++) {
            dst[16 + p] = pack2(b1[j0 + 2 * p], b1[j0 + 2 * p + 1]);
            dst[20 + p] = pack2(W2[(j0 + 2 * p) * 2 + 0], W2[(j0 + 2 * p + 1) * 2 + 0]);
            dst[24 + p] = pack2(W2[(j0 + 2 * p) * 2 + 1], W2[(j0 + 2 * p + 1) * 2 + 1]);
            dst[28 + p] = 0.0f;
        }
    } else if (t < 40) {
        int c = t - 32, j0 = c * 8;
        float* dst = wpack + 1024 + c * 48;
        for (int p = 0; p < 4; p++) {
            dst[p]      = pack2(finW1[j0 + 2 * p],      finW1[j0 + 2 * p + 1]);
            dst[4 + p]  = pack2(finW1[HH + j0 + 2 * p], finW1[HH + j0 + 2 * p + 1]);
            dst[8 + p]  = pack2(finb1[j0 + 2 * p],      finb1[j0 + 2 * p + 1]);
            dst[12 + p] = 0.0f;
        }
        for (int jp = 0; jp < 4; jp++)
            for (int cc = 0; cc < NC; cc++)
                dst[16 + jp * 8 + cc] = pack2(finW2[(j0 + 2 * jp) * NC + cc],
                                              finW2[(j0 + 2 * jp + 1) * NC + cc]);
    }
}

// ---- fused input projections; e stored as duplicated-f16 pairs ----
__global__ __launch_bounds__(256) void prep_kernel(
    const float* __restrict__ node_feat, const float* __restrict__ edge_attr,
    const float* __restrict__ Wn, const float* __restrict__ bn,
    const float* __restrict__ We, const float* __restrict__ be,
    float* __restrict__ h, unsigned int* __restrict__ ep)
{
    sf16 wn0 = sload16(Wn);
    sf16 wn1 = sload16(Wn + 16);
    sf2  bnv = sload2(bn);
    sf16 wev = sload16(We);
    sf2  bev = sload2(be);
    SWAIT5(wn0, wn1, bnv, wev, bev);

    int idx = blockIdx.x * 256 + threadIdx.x;
    if (idx < NN) {
        const float4* x4 = (const float4*)(node_feat + (size_t)idx * NIN);
        float4 v0 = x4[0], v1 = x4[1], v2 = x4[2], v3 = x4[3];
        float xs[16] = {v0.x, v0.y, v0.z, v0.w, v1.x, v1.y, v1.z, v1.w,
                        v2.x, v2.y, v2.z, v2.w, v3.x, v3.y, v3.z, v3.w};
        float a0 = bnv.x, a1 = bnv.y;
#pragma unroll
        for (int i = 0; i < 8; i++) {
            a0 = fmaf(xs[i], wn0[2 * i], a0);
            a1 = fmaf(xs[i], wn0[2 * i + 1], a1);
        }
#pragma unroll
        for (int i = 0; i < 8; i++) {
            a0 = fmaf(xs[8 + i], wn1[2 * i], a0);
            a1 = fmaf(xs[8 + i], wn1[2 * i + 1], a1);
        }
        ((float2*)h)[idx] = make_float2(a0, a1);
    } else if (idx < NN + EE) {
        int eidx = idx - NN;
        const float4* x4 = (const float4*)(edge_attr + (size_t)eidx * EIN);
        float4 v0 = x4[0], v1 = x4[1];
        float xs[8] = {v0.x, v0.y, v0.z, v0.w, v1.x, v1.y, v1.z, v1.w};
        float a0 = bev.x, a1 = bev.y;
#pragma unroll
        for (int i = 0; i < 8; i++) {
            a0 = fmaf(xs[i], wev[2 * i], a0);
            a1 = fmaf(xs[i], wev[2 * i + 1], a1);
        }
        uint2 pe;
        pe.x = __builtin_bit_cast(unsigned int, dup16(a0));
        pe.y = __builtin_bit_cast(unsigned int, dup16(a1));
        ((uint2*)ep)[eidx] = pe;
    }
}

// ---- one GNN layer; packed-f16 VALU, f32 accumulation via v_dot2_f32_f16 ----
template<bool FINAL>
__global__ __launch_bounds__(256) void layer_kernel(
    const float* __restrict__ h_in, const unsigned int* __restrict__ eP,
    const int* __restrict__ nbr,
    const float* __restrict__ mblk, const float* __restrict__ mb2,
    const float* __restrict__ ublk, const float* __restrict__ ub2,
    float* __restrict__ h_out,
    const float* __restrict__ fblk, const float* __restrict__ fb2,
    float* __restrict__ out)
{
    int i = blockIdx.x * 256 + threadIdx.x;
    if (i >= NN) return;

    sf2 mb2v = sload2(mb2);
    sf2 ub2v = sload2(ub2);
    SWAIT2(mb2v, ub2v);

    float2 hh = ((const float2*)h_in)[i];
    int base = i * KK;
    int n0 = nbr[base + 0], n1 = nbr[base + 1], n2 = nbr[base + 2];
    float2 g0 = ((const float2*)h_in)[n0];
    float2 g1 = ((const float2*)h_in)[n1];
    float2 g2 = ((const float2*)h_in)[n2];
    uint2 pe0 = ((const uint2*)eP)[base + 0];
    uint2 pe1 = ((const uint2*)eP)[base + 1];
    uint2 pe2 = ((const uint2*)eP)[base + 2];
    h2 e0x = bch2u(pe0.x), e0y = bch2u(pe0.y);
    h2 e1x = bch2u(pe1.x), e1y = bch2u(pe1.y);
    h2 e2x = bch2u(pe2.x), e2y = bch2u(pe2.y);
    h2 n0x = dup16(g0.x), n0y = dup16(g0.y);
    h2 n1x = dup16(g1.x), n1y = dup16(g1.y);
    h2 n2x = dup16(g2.x), n2y = dup16(g2.y);

    // aggr = (sum_e leaky([e,hn]@W1+b1)) @ W2 + 3*b2  (linearity of segment_sum)
    float a0 = 3.0f * mb2v.x, a1 = 3.0f * mb2v.y;
#pragma unroll 1
    for (int c = 0; c < 8; c++) {
        sf16 A = sload16(mblk + c * 32);
        sf16 B = sload16(mblk + c * 32 + 16);
        SWAIT2(A, B);
#pragma unroll
        for (int jp = 0; jp < 4; jp++) {
            h2 w0 = bch2(A[jp]), w1 = bch2(A[4 + jp]);
            h2 w2 = bch2(A[8 + jp]), w3 = bch2(A[12 + jp]);
            h2 bb = bch2(B[jp]);
            h2 t0 = PKFMA(e0x, w0, PKFMA(e0y, w1, PKFMA(n0x, w2, PKFMA(n0y, w3, bb))));
            h2 t1 = PKFMA(e1x, w0, PKFMA(e1y, w1, PKFMA(n1x, w2, PKFMA(n1y, w3, bb))));
            h2 t2 = PKFMA(e2x, w0, PKFMA(e2y, w1, PKFMA(n2x, w2, PKFMA(n2y, w3, bb))));
            h2 ts = lk2(t0) + lk2(t1) + lk2(t2);
            a0 = fdot2(ts, bch2(B[4 + jp]), a0);
            a1 = fdot2(ts, bch2(B[8 + jp]), a1);
        }
    }

    // update MLP on concat(h, aggr)
    h2 hx = dup16(hh.x), hy = dup16(hh.y), ax = dup16(a0), ay = dup16(a1);
    float u0 = ub2v.x, u1 = ub2v.y;
#pragma unroll 1
    for (int c = 0; c < 8; c++) {
        sf16 A = sload16(ublk + c * 32);
        sf16 B = sload16(ublk + c * 32 + 16);
        SWAIT2(A, B);
#pragma unroll
        for (int jp = 0; jp < 4; jp++) {
            h2 tt = PKFMA(hx, bch2(A[jp]),
                    PKFMA(hy, bch2(A[4 + jp]),
                    PKFMA(ax, bch2(A[8 + jp]),
                    PKFMA(ay, bch2(A[12 + jp]), bch2(B[jp])))));
            tt = lk2(tt);
            u0 = fdot2(tt, bch2(B[4 + jp]), u0);
            u1 = fdot2(tt, bch2(B[8 + jp]), u1);
        }
    }
    float nh0 = fmaxf(hh.x + u0, 0.0f);
    float nh1 = fmaxf(hh.y + u1, 0.0f);

    if (!FINAL) {
        ((float2*)h_out)[i] = make_float2(nh0, nh1);
    } else {
        sf8 fb2v = sload8(fb2);
        SWAIT1(fb2v);
        float o[NC];
#pragma unroll
        for (int cc = 0; cc < NC; cc++) o[cc] = fb2v[cc];
        h2 nx = dup16(nh0), ny = dup16(nh1);
#pragma unroll 1
        for (int c = 0; c < 8; c++) {
            sf16 A = sload16(fblk + c * 48);
            sf16 B = sload16(fblk + c * 48 + 16);
            sf16 C = sload16(fblk + c * 48 + 32);
            SWAIT3(A, B, C);
#pragma unroll
            for (int jp = 0; jp < 4; jp++) {
                h2 tt = lk2(PKFMA(nx, bch2(A[jp]), PKFMA(ny, bch2(A[4 + jp]), bch2(A[8 + jp]))));
#pragma unroll
                for (int cc = 0; cc < NC; cc++) {
                    float w = (jp < 2) ? B[(jp & 1) * 8 + cc] : C[(jp & 1) * 8 + cc];
                    o[cc] = fdot2(tt, bch2(w), o[cc]);
                }
            }
        }
        float4* op = (float4*)(out + (size_t)i * NC);
        op[0] = make_float4(o[0], o[1], o[2], o[3]);
        op[1] = make_float4(o[4], o[5], o[6], o[7]);
    }
}

extern "C" void kernel_launch(void* const* d_in, const int* in_sizes, int n_in,
                              void* d_out, int out_size, void* d_ws, size_t ws_size,
                              hipStream_t stream) {
    const float* node_feat = (const float*)d_in[0];
    const float* edge_attr = (const float*)d_in[1];
    const int* edge_index = (const int*)d_in[2];
    // d_in[3] = batch (unused)
    const float* Wn = (const float*)d_in[4];
    const float* bn = (const float*)d_in[5];
    const float* We = (const float*)d_in[6];
    const float* be = (const float*)d_in[7];
    const float* msgW1 = (const float*)d_in[8];
    const float* msgb1 = (const float*)d_in[9];
    const float* msgW2 = (const float*)d_in[10];
    const float* msgb2 = (const float*)d_in[11];
    const float* updW1 = (const float*)d_in[12];
    const float* updb1 = (const float*)d_in[13];
    const float* updW2 = (const float*)d_in[14];
    const float* updb2 = (const float*)d_in[15];
    const float* finW1 = (const float*)d_in[16];
    const float* finb1 = (const float*)d_in[17];
    const float* finW2 = (const float*)d_in[18];
    const float* finb2 = (const float*)d_in[19];
    float* out = (float*)d_out;

    const int* nbr = edge_index + EE;  // edge_index[1] row

    char* ws = (char*)d_ws;
    float* hA = (float*)ws;                                      // 4 MB
    float* hB = (float*)(ws + (size_t)NN * 2 * 4);               // 4 MB
    unsigned int* eP = (unsigned int*)(ws + (size_t)NN * 4 * 4); // 12 MB (E x 2 dwords)
    float* wpack = (float*)(ws + (size_t)NN * 4 * 4 + (size_t)EE * 2 * 4); // ~6 KB

    pack_kernel<<<1, 64, 0, stream>>>(msgW1, msgb1, msgW2,
                                      updW1, updb1, updW2,
                                      finW1, finb1, finW2, wpack);

    const int threads = 256;
    int prep_grid = (NN + EE + threads - 1) / threads;
    prep_kernel<<<prep_grid, threads, 0, stream>>>(node_feat, edge_attr, Wn, bn, We, be, hA, eP);

    int grid = (NN + threads - 1) / threads;
    // wpack blocks: (l*2 + which)*256 dwords; final at 1024
    layer_kernel<false><<<grid, threads, 0, stream>>>(
        hA, eP, nbr,
        wpack + 0 * 256, msgb2,
        wpack + 1 * 256, updb2,
        hB, wpack + 1024, finb2, nullptr);
    layer_kernel<true><<<grid, threads, 0, stream>>>(
        hB, eP, nbr,
        wpack + 2 * 256, msgb2 + 2,
        wpack + 3 * 256, updb2 + 2,
        nullptr, wpack + 1024, finb2, out);
}

// Round 6
// 198.448 us; speedup vs baseline: 1.1454x; 1.0314x over previous
//
#include <hip/hip_runtime.h>

#define NN 500000
#define HALF 250000
#define KK 3
#define EE (NN * KK)
#define HH 64
#define NC 8
#define NIN 16
#define EIN 8

typedef __attribute__((ext_vector_type(2))) _Float16 h2;
typedef __attribute__((ext_vector_type(2)))  float sf2;
typedef __attribute__((ext_vector_type(8)))  float sf8;
typedef __attribute__((ext_vector_type(16))) float sf16;

// The builtins' own half-pair type (clang spells it __fp16 ext_vector(2)).
using pk_t = decltype(__builtin_amdgcn_cvt_pkrtz(0.f, 0.f));

// Guaranteed-scalar loads of wave-uniform weight data (K$-cached, scalar pipe).
__device__ __forceinline__ sf2 sload2(const float* p) {
    sf2 r; asm("s_load_dwordx2 %0, %1, 0x0" : "=s"(r) : "s"(p)); return r;
}
__device__ __forceinline__ sf8 sload8(const float* p) {
    sf8 r; asm("s_load_dwordx8 %0, %1, 0x0" : "=s"(r) : "s"(p)); return r;
}
__device__ __forceinline__ sf16 sload16(const float* p) {
    sf16 r; asm("s_load_dwordx16 %0, %1, 0x0" : "=s"(r) : "s"(p)); return r;
}
#define SWAIT1(a)         asm volatile("s_waitcnt lgkmcnt(0)" : "+s"(a))
#define SWAIT2(a,b)       asm volatile("s_waitcnt lgkmcnt(0)" : "+s"(a),"+s"(b))
#define SWAIT3(a,b,c)     asm volatile("s_waitcnt lgkmcnt(0)" : "+s"(a),"+s"(b),"+s"(c))
#define SWAIT4(a,b,c,d)   asm volatile("s_waitcnt lgkmcnt(0)" : "+s"(a),"+s"(b),"+s"(c),"+s"(d))
#define SWAIT5(a,b,c,d,e) asm volatile("s_waitcnt lgkmcnt(0)" : "+s"(a),"+s"(b),"+s"(c),"+s"(d),"+s"(e))

#if __has_builtin(__builtin_elementwise_fma)
#define PKFMA(a,b,c) __builtin_elementwise_fma((a),(b),(c))
#else
#define PKFMA(a,b,c) ((a)*(b)+(c))
#endif

__device__ __forceinline__ h2 bch2(float f)        { return __builtin_bit_cast(h2, f); }
__device__ __forceinline__ h2 bch2u(unsigned int u){ return __builtin_bit_cast(h2, u); }
__device__ __forceinline__ h2 dup16(float f) {
    return __builtin_bit_cast(h2, __builtin_amdgcn_cvt_pkrtz(f, f));
}
__device__ __forceinline__ unsigned int pkrtz_u(float a, float b) {
    return __builtin_bit_cast(unsigned int, __builtin_amdgcn_cvt_pkrtz(a, b));
}
// splat low/high f16 of a packed u32 into both lanes
__device__ __forceinline__ h2 splat_lo(unsigned int u) {
    h2 p = bch2u(u); h2 r; r.x = p.x; r.y = p.x; return r;
}
__device__ __forceinline__ h2 splat_hi(unsigned int u) {
    h2 p = bch2u(u); h2 r; r.x = p.y; r.y = p.y; return r;
}
__device__ __forceinline__ float lo_f32(unsigned int u) { return (float)bch2u(u).x; }
__device__ __forceinline__ float hi_f32(unsigned int u) { return (float)bch2u(u).y; }

__device__ __forceinline__ float fdot2(h2 a, h2 b, float c) {
#if __has_builtin(__builtin_amdgcn_fdot2)
    return __builtin_amdgcn_fdot2(__builtin_bit_cast(pk_t, a),
                                  __builtin_bit_cast(pk_t, b), c, false);
#else
    return c + (float)a.x * (float)b.x + (float)a.y * (float)b.y;
#endif
}
__device__ __forceinline__ h2 lk2(h2 x) {
    h2 c = {(_Float16)0.1f, (_Float16)0.1f};
    return __builtin_elementwise_max(x, x * c);
}
__device__ __forceinline__ float pack2(float a, float b) {
    h2 v; v.x = (_Float16)a; v.y = (_Float16)b;   // RTN conversion for weights
    return __builtin_bit_cast(float, v);
}

// ---- fused input projections (packed u32 outputs) + inline weight packing ----
// wpack layout: msg/upd block (l*2+which)*256 dwords, 8 chunks x 32 dwords:
//   [0:3]=W1row0 pairs, [4:7]=row1, [8:11]=row2, [12:15]=row3,
//   [16:19]=b1 pairs, [20:23]=W2[:,0] pairs, [24:27]=W2[:,1] pairs, [28:31]=pad
// final block at 1024: 8 chunks x 48 dwords:
//   [0:3]=fW1row0 pairs, [4:7]=row1, [8:11]=fb1 pairs, [12:15]=pad,
//   [16+jp*8+c] = pack(fW2[j0+2jp][c], fW2[j0+2jp+1][c])
__global__ __launch_bounds__(256) void prep_kernel(
    const float* __restrict__ node_feat, const float* __restrict__ edge_attr,
    const float* __restrict__ Wn, const float* __restrict__ bn,
    const float* __restrict__ We, const float* __restrict__ be,
    unsigned int* __restrict__ hp, unsigned int* __restrict__ ep,
    const float* __restrict__ msgW1, const float* __restrict__ msgb1, const float* __restrict__ msgW2,
    const float* __restrict__ updW1, const float* __restrict__ updb1, const float* __restrict__ updW2,
    const float* __restrict__ finW1, const float* __restrict__ finb1, const float* __restrict__ finW2,
    float* __restrict__ wpack)
{
    sf16 wn0 = sload16(Wn);
    sf16 wn1 = sload16(Wn + 16);
    sf2  bnv = sload2(bn);
    sf16 wev = sload16(We);
    sf2  bev = sload2(be);
    SWAIT5(wn0, wn1, bnv, wev, bev);

    int idx = blockIdx.x * 256 + threadIdx.x;
    if (idx < NN) {
        const float4* x4 = (const float4*)(node_feat + (size_t)idx * NIN);
        float4 v0 = x4[0], v1 = x4[1], v2 = x4[2], v3 = x4[3];
        float xs[16] = {v0.x, v0.y, v0.z, v0.w, v1.x, v1.y, v1.z, v1.w,
                        v2.x, v2.y, v2.z, v2.w, v3.x, v3.y, v3.z, v3.w};
        float a0 = bnv.x, a1 = bnv.y;
#pragma unroll
        for (int i = 0; i < 8; i++) {
            a0 = fmaf(xs[i], wn0[2 * i], a0);
            a1 = fmaf(xs[i], wn0[2 * i + 1], a1);
        }
#pragma unroll
        for (int i = 0; i < 8; i++) {
            a0 = fmaf(xs[8 + i], wn1[2 * i], a0);
            a1 = fmaf(xs[8 + i], wn1[2 * i + 1], a1);
        }
        hp[idx] = pkrtz_u(a0, a1);
    } else if (idx < NN + EE) {
        int eidx = idx - NN;
        const float4* x4 = (const float4*)(edge_attr + (size_t)eidx * EIN);
        float4 v0 = x4[0], v1 = x4[1];
        float xs[8] = {v0.x, v0.y, v0.z, v0.w, v1.x, v1.y, v1.z, v1.w};
        float a0 = bev.x, a1 = bev.y;
#pragma unroll
        for (int i = 0; i < 8; i++) {
            a0 = fmaf(xs[i], wev[2 * i], a0);
            a1 = fmaf(xs[i], wev[2 * i + 1], a1);
        }
        ep[eidx] = pkrtz_u(a0, a1);
    }

    // ---- inline weight packing (block 0 only; tiny serial side-work) ----
    if (blockIdx.x == 0) {
        int t = threadIdx.x;
        if (t < 32) {
            int l = t >> 4, which = (t >> 3) & 1, c = t & 7;
            const float* W1 = (which ? updW1 : msgW1) + l * 4 * HH;
            const float* b1 = (which ? updb1 : msgb1) + l * HH;
            const float* W2 = (which ? updW2 : msgW2) + l * 2 * HH;
            float* dst = wpack + (l * 2 + which) * 256 + c * 32;
            int j0 = c * 8;
            for (int r = 0; r < 4; r++)
                for (int p = 0; p < 4; p++)
                    dst[r * 4 + p] = pack2(W1[r * HH + j0 + 2 * p], W1[r * HH + j0 + 2 * p + 1]);
            for (int p = 0; p < 4; p++) {
                dst[16 + p] = pack2(b1[j0 + 2 * p], b1[j0 + 2 * p + 1]);
                dst[20 + p] = pack2(W2[(j0 + 2 * p) * 2 + 0], W2[(j0 + 2 * p + 1) * 2 + 0]);
                dst[24 + p] = pack2(W2[(j0 + 2 * p) * 2 + 1], W2[(j0 + 2 * p + 1) * 2 + 1]);
                dst[28 + p] = 0.0f;
            }
        } else if (t < 40) {
            int c = t - 32, j0 = c * 8;
            float* dst = wpack + 1024 + c * 48;
            for (int p = 0; p < 4; p++) {
                dst[p]      = pack2(finW1[j0 + 2 * p],      finW1[j0 + 2 * p + 1]);
                dst[4 + p]  = pack2(finW1[HH + j0 + 2 * p], finW1[HH + j0 + 2 * p + 1]);
                dst[8 + p]  = pack2(finb1[j0 + 2 * p],      finb1[j0 + 2 * p + 1]);
                dst[12 + p] = 0.0f;
            }
            for (int jp = 0; jp < 4; jp++)
                for (int cc = 0; cc < NC; cc++)
                    dst[16 + jp * 8 + cc] = pack2(finW2[(j0 + 2 * jp) * NC + cc],
                                                  finW2[(j0 + 2 * jp + 1) * NC + cc]);
        }
    }
}

// ---- one GNN layer; 2 nodes/thread, packed-f16 VALU, f32 accumulation ----
template<bool FINAL>
__global__ __launch_bounds__(256) void layer_kernel(
    const unsigned int* __restrict__ hp_in, const unsigned int* __restrict__ eP,
    const int* __restrict__ nbr,
    const float* __restrict__ mblk, const float* __restrict__ mb2,
    const float* __restrict__ ublk, const float* __restrict__ ub2,
    unsigned int* __restrict__ hp_out,
    const float* __restrict__ fblk, const float* __restrict__ fb2,
    float* __restrict__ out)
{
    int tA = blockIdx.x * 256 + threadIdx.x;
    if (tA >= HALF) return;
    int iA = tA, iB = tA + HALF;

    sf2 mb2v = sload2(mb2);
    sf2 ub2v = sload2(ub2);
    SWAIT2(mb2v, ub2v);

    unsigned int hA = hp_in[iA], hB = hp_in[iB];
    int baseA = iA * KK, baseB = iB * KK;
    int nA0 = nbr[baseA], nA1 = nbr[baseA + 1], nA2 = nbr[baseA + 2];
    int nB0 = nbr[baseB], nB1 = nbr[baseB + 1], nB2 = nbr[baseB + 2];
    unsigned int gA0 = hp_in[nA0], gA1 = hp_in[nA1], gA2 = hp_in[nA2];
    unsigned int gB0 = hp_in[nB0], gB1 = hp_in[nB1], gB2 = hp_in[nB2];
    unsigned int eA0 = eP[baseA], eA1 = eP[baseA + 1], eA2 = eP[baseA + 2];
    unsigned int eB0 = eP[baseB], eB1 = eP[baseB + 1], eB2 = eP[baseB + 2];

    h2 eA0x = splat_lo(eA0), eA0y = splat_hi(eA0);
    h2 eA1x = splat_lo(eA1), eA1y = splat_hi(eA1);
    h2 eA2x = splat_lo(eA2), eA2y = splat_hi(eA2);
    h2 eB0x = splat_lo(eB0), eB0y = splat_hi(eB0);
    h2 eB1x = splat_lo(eB1), eB1y = splat_hi(eB1);
    h2 eB2x = splat_lo(eB2), eB2y = splat_hi(eB2);
    h2 nA0x = splat_lo(gA0), nA0y = splat_hi(gA0);
    h2 nA1x = splat_lo(gA1), nA1y = splat_hi(gA1);
    h2 nA2x = splat_lo(gA2), nA2y = splat_hi(gA2);
    h2 nB0x = splat_lo(gB0), nB0y = splat_hi(gB0);
    h2 nB1x = splat_lo(gB1), nB1y = splat_hi(gB1);
    h2 nB2x = splat_lo(gB2), nB2y = splat_hi(gB2);

    // aggr = (sum_e leaky([e,hn]@W1+b1)) @ W2 + 3*b2  (linearity of segment_sum)
    float a0A = 3.0f * mb2v.x, a1A = 3.0f * mb2v.y;
    float a0B = a0A, a1B = a1A;
#pragma unroll 1
    for (int c = 0; c < 8; c += 2) {
        sf16 A0 = sload16(mblk + c * 32);
        sf16 B0 = sload16(mblk + c * 32 + 16);
        sf16 A1 = sload16(mblk + c * 32 + 32);
        sf16 B1 = sload16(mblk + c * 32 + 48);
        SWAIT4(A0, B0, A1, B1);
#pragma unroll
        for (int half = 0; half < 2; half++) {
            const sf16& A = half ? A1 : A0;
            const sf16& B = half ? B1 : B0;
#pragma unroll
            for (int jp = 0; jp < 4; jp++) {
                h2 w0 = bch2(A[jp]), w1 = bch2(A[4 + jp]);
                h2 w2 = bch2(A[8 + jp]), w3 = bch2(A[12 + jp]);
                h2 bb = bch2(B[jp]);
                h2 wcx = bch2(B[4 + jp]), wcy = bch2(B[8 + jp]);
                h2 t0 = PKFMA(eA0x, w0, PKFMA(eA0y, w1, PKFMA(nA0x, w2, PKFMA(nA0y, w3, bb))));
                h2 t1 = PKFMA(eA1x, w0, PKFMA(eA1y, w1, PKFMA(nA1x, w2, PKFMA(nA1y, w3, bb))));
                h2 t2 = PKFMA(eA2x, w0, PKFMA(eA2y, w1, PKFMA(nA2x, w2, PKFMA(nA2y, w3, bb))));
                h2 tsA = lk2(t0) + lk2(t1) + lk2(t2);
                a0A = fdot2(tsA, wcx, a0A);
                a1A = fdot2(tsA, wcy, a1A);
                h2 s0 = PKFMA(eB0x, w0, PKFMA(eB0y, w1, PKFMA(nB0x, w2, PKFMA(nB0y, w3, bb))));
                h2 s1 = PKFMA(eB1x, w0, PKFMA(eB1y, w1, PKFMA(nB1x, w2, PKFMA(nB1y, w3, bb))));
                h2 s2 = PKFMA(eB2x, w0, PKFMA(eB2y, w1, PKFMA(nB2x, w2, PKFMA(nB2y, w3, bb))));
                h2 tsB = lk2(s0) + lk2(s1) + lk2(s2);
                a0B = fdot2(tsB, wcx, a0B);
                a1B = fdot2(tsB, wcy, a1B);
            }
        }
    }

    // update MLP on concat(h, aggr)
    h2 hAx = splat_lo(hA), hAy = splat_hi(hA);
    h2 hBx = splat_lo(hB), hBy = splat_hi(hB);
    h2 aAx = dup16(a0A), aAy = dup16(a1A);
    h2 aBx = dup16(a0B), aBy = dup16(a1B);
    float u0A = ub2v.x, u1A = ub2v.y, u0B = ub2v.x, u1B = ub2v.y;
#pragma unroll 1
    for (int c = 0; c < 8; c += 2) {
        sf16 A0 = sload16(ublk + c * 32);
        sf16 B0 = sload16(ublk + c * 32 + 16);
        sf16 A1 = sload16(ublk + c * 32 + 32);
        sf16 B1 = sload16(ublk + c * 32 + 48);
        SWAIT4(A0, B0, A1, B1);
#pragma unroll
        for (int half = 0; half < 2; half++) {
            const sf16& A = half ? A1 : A0;
            const sf16& B = half ? B1 : B0;
#pragma unroll
            for (int jp = 0; jp < 4; jp++) {
                h2 w0 = bch2(A[jp]), w1 = bch2(A[4 + jp]);
                h2 w2 = bch2(A[8 + jp]), w3 = bch2(A[12 + jp]);
                h2 bb = bch2(B[jp]);
                h2 wcx = bch2(B[4 + jp]), wcy = bch2(B[8 + jp]);
                h2 tt = PKFMA(hAx, w0, PKFMA(hAy, w1, PKFMA(aAx, w2, PKFMA(aAy, w3, bb))));
                tt = lk2(tt);
                u0A = fdot2(tt, wcx, u0A);
                u1A = fdot2(tt, wcy, u1A);
                h2 ss = PKFMA(hBx, w0, PKFMA(hBy, w1, PKFMA(aBx, w2, PKFMA(aBy, w3, bb))));
                ss = lk2(ss);
                u0B = fdot2(ss, wcx, u0B);
                u1B = fdot2(ss, wcy, u1B);
            }
        }
    }
    float nhA0 = fmaxf(lo_f32(hA) + u0A, 0.0f);
    float nhA1 = fmaxf(hi_f32(hA) + u1A, 0.0f);
    float nhB0 = fmaxf(lo_f32(hB) + u0B, 0.0f);
    float nhB1 = fmaxf(hi_f32(hB) + u1B, 0.0f);

    if constexpr (!FINAL) {
        hp_out[iA] = pkrtz_u(nhA0, nhA1);
        hp_out[iB] = pkrtz_u(nhB0, nhB1);
    } else {
        sf8 fb2v = sload8(fb2);
        SWAIT1(fb2v);
        float oA[NC], oB[NC];
#pragma unroll
        for (int cc = 0; cc < NC; cc++) { oA[cc] = fb2v[cc]; oB[cc] = fb2v[cc]; }
        h2 nAx = dup16(nhA0), nAy = dup16(nhA1);
        h2 nBx = dup16(nhB0), nBy = dup16(nhB1);
#pragma unroll 1
        for (int c = 0; c < 8; c++) {
            sf16 A = sload16(fblk + c * 48);
            sf16 B = sload16(fblk + c * 48 + 16);
            sf16 C = sload16(fblk + c * 48 + 32);
            SWAIT3(A, B, C);
#pragma unroll
            for (int jp = 0; jp < 4; jp++) {
                h2 w1a = bch2(A[jp]), w1b = bch2(A[4 + jp]), bb = bch2(A[8 + jp]);
                h2 ttA = lk2(PKFMA(nAx, w1a, PKFMA(nAy, w1b, bb)));
                h2 ttB = lk2(PKFMA(nBx, w1a, PKFMA(nBy, w1b, bb)));
#pragma unroll
                for (int cc = 0; cc < NC; cc++) {
                    float w = (jp < 2) ? B[(jp & 1) * 8 + cc] : C[(jp & 1) * 8 + cc];
                    h2 wv = bch2(w);
                    oA[cc] = fdot2(ttA, wv, oA[cc]);
                    oB[cc] = fdot2(ttB, wv, oB[cc]);
                }
            }
        }
        float4* opA = (float4*)(out + (size_t)iA * NC);
        opA[0] = make_float4(oA[0], oA[1], oA[2], oA[3]);
        opA[1] = make_float4(oA[4], oA[5], oA[6], oA[7]);
        float4* opB = (float4*)(out + (size_t)iB * NC);
        opB[0] = make_float4(oB[0], oB[1], oB[2], oB[3]);
        opB[1] = make_float4(oB[4], oB[5], oB[6], oB[7]);
    }
}

extern "C" void kernel_launch(void* const* d_in, const int* in_sizes, int n_in,
                              void* d_out, int out_size, void* d_ws, size_t ws_size,
                              hipStream_t stream) {
    const float* node_feat = (const float*)d_in[0];
    const float* edge_attr = (const float*)d_in[1];
    const int* edge_index = (const int*)d_in[2];
    // d_in[3] = batch (unused)
    const float* Wn = (const float*)d_in[4];
    const float* bn = (const float*)d_in[5];
    const float* We = (const float*)d_in[6];
    const float* be = (const float*)d_in[7];
    const float* msgW1 = (const float*)d_in[8];
    const float* msgb1 = (const float*)d_in[9];
    const float* msgW2 = (const float*)d_in[10];
    const float* msgb2 = (const float*)d_in[11];
    const float* updW1 = (const float*)d_in[12];
    const float* updb1 = (const float*)d_in[13];
    const float* updW2 = (const float*)d_in[14];
    const float* updb2 = (const float*)d_in[15];
    const float* finW1 = (const float*)d_in[16];
    const float* finb1 = (const float*)d_in[17];
    const float* finW2 = (const float*)d_in[18];
    const float* finb2 = (const float*)d_in[19];
    float* out = (float*)d_out;

    const int* nbr = edge_index + EE;  // edge_index[1] row

    char* ws = (char*)d_ws;
    unsigned int* hA = (unsigned int*)ws;                         // NN u32 (2 MB)
    unsigned int* hB = (unsigned int*)(ws + (size_t)NN * 4);      // NN u32 (2 MB)
    unsigned int* eP = (unsigned int*)(ws + (size_t)NN * 8);      // EE u32 (6 MB)
    float* wpack = (float*)(ws + (size_t)NN * 8 + (size_t)EE * 4);// ~5.6 KB

    const int threads = 256;
    int prep_grid = (NN + EE + threads - 1) / threads;
    prep_kernel<<<prep_grid, threads, 0, stream>>>(
        node_feat, edge_attr, Wn, bn, We, be, hA, eP,
        msgW1, msgb1, msgW2, updW1, updb1, updW2,
        finW1, finb1, finW2, wpack);

    int grid = (HALF + threads - 1) / threads;
    // wpack blocks: (l*2 + which)*256 dwords; final at 1024
    layer_kernel<false><<<grid, threads, 0, stream>>>(
        hA, eP, nbr,
        wpack + 0 * 256, msgb2,
        wpack + 1 * 256, updb2,
        hB, wpack + 1024, finb2, nullptr);
    layer_kernel<true><<<grid, threads, 0, stream>>>(
        hB, eP, nbr,
        wpack + 2 * 256, msgb2 + 2,
        wpack + 3 * 256, updb2 + 2,
        nullptr, wpack + 1024, finb2, out);
}